// Round 7
// baseline (279.814 us; speedup 1.0000x reference)
//
#include <hip/hip_runtime.h>
#include <math.h>

// Problem constants (x: [4, 64, 384, 384] fp32)
#define QLS_T    256             // B*C = 4*64, sequential scan axis
#define QLS_HW   (384 * 384)     // independent spatial locations (147456)
#define QLS_HW4  (QLS_HW / 4)    // float4 granularity (36864)
#define CHUNK    16              // parallel t-chunks (re-associated scan)
#define TPC      (QLS_T / CHUNK) // 16 planes per chunk
#define TILES    36              // location tiles per chunk in K1
#define TILE_LOC 4096            // locations per tile (16KB contiguous per plane)

// Quantizer constants from the reference
#define Q_SCALE      16.0f
#define INV_Q_SCALE  (1.0f / 16.0f)
#define QMAXF        7.9375f
#define QMINF        (-8.0f)
#define LUT_IN_SCALE 4096.0f
#define LUT_IN_MAX   32767.0f
#define INV_LUT_OUT  (1.0f / 65536.0f)

// log1p(exp(-d)) = log2(1 + 2^(-d*log2e)) * ln2, on raw v_exp_f32/v_log_f32.
#define NEG_LOG2E_DIV (-1.4426950408889634f / 4096.0f)
#define LN2_X_65536   45426.09375f

// Native clang vector type (HIP float4 is rejected by nontemporal builtin).
typedef float f32x4 __attribute__((ext_vector_type(4)));

__device__ __forceinline__ float qls_step(float s, float v) {
    float diff = fabsf(s - v);
    float d_int = fminf(floorf(diff * LUT_IN_SCALE), LUT_IN_MAX);
    float e  = __builtin_amdgcn_exp2f(d_int * NEG_LOG2E_DIV);
    float lu = rintf(__builtin_amdgcn_logf(1.0f + e) * LN2_X_65536) * INV_LUT_OUT;
    s = fmaxf(s, v) + lu;
    return fminf(fmaxf(s, QMINF), QMAXF);
}

// ---------------- K1: scan partials with long-contiguous read streams ----
// R9 theory: the ~2.7TB/s wall across ALL prior variants (traffic- and
// occupancy-independent) is DRAM row thrash from 256B-1KB spans at 576KB
// plane stride. Here each block reads 16KB contiguous per plane (1024
// threads x f32x4), 16 planes per block -> the aggregate stream is made of
// 16KB sequential spans instead of 1KB. Partials (chunk c covers planes
// [16c,16c+16) in t-order) go to workspace contiguously.
__global__ __launch_bounds__(1024) void qls_k1_scan(
    const float* __restrict__ x, float* __restrict__ part) {
    const int c    = blockIdx.x / TILES;           // t-chunk, 0..15
    const int tile = blockIdx.x % TILES;           // location tile, 0..35
    const int loc  = tile * TILE_LOC + threadIdx.x * 4;  // 4 consecutive locs
    const float* xp = x + (size_t)c * TPC * QLS_HW + loc;

    float s0 = QMINF, s1 = QMINF, s2 = QMINF, s3 = QMINF;
    #pragma unroll
    for (int k = 0; k < TPC; ++k) {
        f32x4 v = *reinterpret_cast<const f32x4*>(xp + (size_t)k * QLS_HW);
        s0 = qls_step(s0, v.x); s1 = qls_step(s1, v.y);
        s2 = qls_step(s2, v.z); s3 = qls_step(s3, v.w);
    }
    f32x4 sv; sv.x = s0; sv.y = s1; sv.z = s2; sv.w = s3;
    // part[c][loc]: plain store (K2 re-reads it; keep cached)
    *reinterpret_cast<f32x4*>(part + (size_t)c * QLS_HW + loc) = sv;
}

// ---------------- K2: merge 16 partials per location (t-order) -----------
// 9.4MB working set, cache-hot, trivially fast. Same quantized op, same
// c-ascending order as R8's in-block merge -> numerics identical to R8.
__global__ __launch_bounds__(256) void qls_k2_merge(
    const float* __restrict__ part, float* __restrict__ sbuf) {
    const int loc = (blockIdx.x * 256 + threadIdx.x) * 4;
    f32x4 t4 = *reinterpret_cast<const f32x4*>(part + loc);
    float t0 = t4.x, t1 = t4.y, t2 = t4.z, t3 = t4.w;
    #pragma unroll
    for (int c = 1; c < CHUNK; ++c) {
        f32x4 p4 = *reinterpret_cast<const f32x4*>(part + (size_t)c * QLS_HW + loc);
        t0 = qls_step(t0, p4.x); t1 = qls_step(t1, p4.y);
        t2 = qls_step(t2, p4.z); t3 = qls_step(t3, p4.w);
    }
    f32x4 sv; sv.x = t0; sv.y = t1; sv.z = t2; sv.w = t3;
    *reinterpret_cast<f32x4*>(sbuf + loc) = sv;
}

// ---------------- K3: elementwise output, loc-fastest sweep --------------
// Consecutive blocks sweep whole planes contiguously (144 blocks per
// t-group): both the x read (L3-warm from K1) and the 1KB NT write stream
// advance sequentially through memory.
__global__ __launch_bounds__(256) void qls_k3_out(
    const float* __restrict__ x, const float* __restrict__ sbuf,
    float* __restrict__ out) {
    const int idx  = blockIdx.x * 256 + threadIdx.x;
    const int loc4 = idx % QLS_HW4;
    const int tb   = (idx / QLS_HW4) * 4;

    const f32x4 s4 = reinterpret_cast<const f32x4*>(sbuf)[loc4];

    #pragma unroll
    for (int k = 0; k < 4; ++k) {
        const int t = tb + k;
        const f32x4 v = reinterpret_cast<const f32x4*>(x + (size_t)t * QLS_HW)[loc4];
        f32x4 q;
        q.x = fminf(fmaxf(rintf((v.x - s4.x) * Q_SCALE), -128.0f), 127.0f) * INV_Q_SCALE;
        q.y = fminf(fmaxf(rintf((v.y - s4.y) * Q_SCALE), -128.0f), 127.0f) * INV_Q_SCALE;
        q.z = fminf(fmaxf(rintf((v.z - s4.z) * Q_SCALE), -128.0f), 127.0f) * INV_Q_SCALE;
        q.w = fminf(fmaxf(rintf((v.w - s4.w) * Q_SCALE), -128.0f), 127.0f) * INV_Q_SCALE;
        __builtin_nontemporal_store(q, reinterpret_cast<f32x4*>(out + (size_t)t * QLS_HW) + loc4);
    }
}

// ---------------- Fallback: R7 chunked fused kernel (best so far) --------
__global__ __launch_bounds__(512, 4) void qls_fused_kernel(
    const float* __restrict__ x, float* __restrict__ out) {
    const int lane  = threadIdx.x & 63;
    const int chunk = threadIdx.x >> 6;               // 0..7
    const int loc   = blockIdx.x * 64 + lane;
    const size_t base = (size_t)loc + (size_t)chunk * 32 * QLS_HW;
    const float* xp = x + base;

    float v[32];
    #pragma unroll
    for (int k = 0; k < 32; ++k) v[k] = xp[(size_t)k * QLS_HW];

    float s = QMINF;
    #pragma unroll
    for (int k = 0; k < 32; ++k) s = qls_step(s, v[k]);

    __shared__ float part[8][64];
    part[chunk][lane] = s;
    __syncthreads();

    float tot = part[0][lane];
    #pragma unroll
    for (int c = 1; c < 8; ++c) tot = qls_step(tot, part[c][lane]);

    float* op = out + base;
    #pragma unroll
    for (int k = 0; k < 32; ++k) {
        float q = fminf(fmaxf(rintf((v[k] - tot) * Q_SCALE), -128.0f), 127.0f);
        __builtin_nontemporal_store(q * INV_Q_SCALE, op + (size_t)k * QLS_HW);
    }
}

extern "C" void kernel_launch(void* const* d_in, const int* in_sizes, int n_in,
                              void* d_out, int out_size, void* d_ws, size_t ws_size,
                              hipStream_t stream) {
    const float* x = (const float*)d_in[0];
    float* out = (float*)d_out;
    const size_t part_bytes = (size_t)CHUNK * QLS_HW * sizeof(float);  // 9.44 MB
    const size_t s_bytes    = (size_t)QLS_HW * sizeof(float);          // 576 KB

    if (d_ws != nullptr && ws_size >= part_bytes + s_bytes) {
        float* part = (float*)d_ws;
        float* sbuf = part + (size_t)CHUNK * QLS_HW;
        qls_k1_scan <<<CHUNK * TILES, 1024, 0, stream>>>(x, part);              // 576 blocks
        qls_k2_merge<<<QLS_HW4 / 256, 256, 0, stream>>>(part, sbuf);            // 144 blocks
        qls_k3_out  <<<(QLS_T / 4) * (QLS_HW4 / 256), 256, 0, stream>>>(x, sbuf, out); // 9216 blocks
    } else {
        qls_fused_kernel<<<QLS_HW / 64, 512, 0, stream>>>(x, out);              // 2304 blocks
    }
}